// Round 11
// baseline (160.810 us; speedup 1.0000x reference)
//
#include <hip/hip_runtime.h>
#include <hip/hip_bf16.h>

// Problem constants
#define S_LEN   4096
#define D_MOD   512
#define BATCH   4
#define HALF_W  128
#define M_TOT   (BATCH * S_LEN)   // 16384

typedef __attribute__((ext_vector_type(8))) short bf16x8;
typedef __attribute__((ext_vector_type(4))) float f32x4;

__device__ __forceinline__ unsigned short f2bf(float f) {
    // round-to-nearest-even bf16 (values are finite here)
    unsigned int u = __float_as_uint(f);
    unsigned int r = (u + 0x7fffu + ((u >> 16) & 1u)) >> 16;
    return (unsigned short)r;
}

__device__ __forceinline__ void async_copy16(const void* g, void* l) {
    __builtin_amdgcn_global_load_lds(
        (const __attribute__((address_space(1))) void*)g,
        (__attribute__((address_space(3))) void*)l, 16, 0, 0);
}

// ---------------------------------------------------------------------------
// Kernel 1: fused converts (byte-identical).
__global__ __launch_bounds__(256) void convert_xw(const float* __restrict__ x,
                                                  const float* __restrict__ Wq,
                                                  const float* __restrict__ Wk,
                                                  const float* __restrict__ Wv,
                                                  unsigned short* __restrict__ xb,
                                                  unsigned short* __restrict__ Wt) {
    __shared__ float sT[64][65];
    const int t = threadIdx.x;
    const int bid = blockIdx.x;
    if (bid < 8192) {
        int i = (bid * 256 + t) * 4;
        float4 v = *(const float4*)(x + i);
        ushort4 o;
        o.x = f2bf(v.x); o.y = f2bf(v.y); o.z = f2bf(v.z); o.w = f2bf(v.w);
        *(ushort4*)(xb + i) = o;
        return;
    }
    const int j = bid - 8192;            // 0..191
    const int w = j >> 6;                // weight select (64 tiles each)
    const int rj = j & 63;
    const float* W = (w == 0) ? Wq : ((w == 1) ? Wk : Wv);
    const int n0 = (rj & 7) * 64, k0 = (rj >> 3) * 64;
    const int r = t >> 4, c4 = (t & 15) * 4;
    #pragma unroll
    for (int i = 0; i < 4; ++i) {
        float4 v = *(const float4*)(W + (size_t)(k0 + r + i * 16) * 512 + n0 + c4);
        sT[c4 + 0][r + i * 16] = v.x;
        sT[c4 + 1][r + i * 16] = v.y;
        sT[c4 + 2][r + i * 16] = v.z;
        sT[c4 + 3][r + i * 16] = v.w;
    }
    __syncthreads();
    #pragma unroll
    for (int i = 0; i < 4; ++i) {
        int rr = (t >> 4) + i * 16;   // n-local
        ushort4 o;
        o.x = f2bf(sT[rr][c4 + 0]);
        o.y = f2bf(sT[rr][c4 + 1]);
        o.z = f2bf(sT[rr][c4 + 2]);
        o.w = f2bf(sT[rr][c4 + 3]);
        *(ushort4*)(Wt + (size_t)w * 262144 + (size_t)(n0 + rr) * 512 + k0 + c4) = o;
    }
}

// ---------------------------------------------------------------------------
// Kernel 2: fused QKV GEMM — v4: depth-2 prefetch, counted vmcnt (T3/T4).
// 3 LDS buffers (A 32KB + B 16KB each, 144 KB total). Per step i:
//   vmcnt(6) [P(i) landed; 6 gload_lds wave-instrs/step, in-order retirement]
//   -> s_barrier + sched_barrier(0)
//   -> issue P(i+2) into buf[(i+2)%3] (readers = compute(i-1), pre-barrier)
//   -> compute buf[i%3].
// Never drains vmcnt to 0 mid-loop; each prefetch has ~2 compute-steps cover.
__global__ __launch_bounds__(512, 1) void qkv_gemm(
    const unsigned short* __restrict__ xb, const unsigned short* __restrict__ Wt,
    const float* __restrict__ bq, const float* __restrict__ bk, const float* __restrict__ bv,
    unsigned short* __restrict__ Qo, unsigned short* __restrict__ Ko,
    unsigned short* __restrict__ Vt) {
    __shared__ __align__(16) char gsmem[147456];
    unsigned short* const sT = (unsigned short*)gsmem;   // epilogue alias

    const int t = threadIdx.x;
    // XCD swizzle over 768 blocks (= 8 * 96)
    const int p = blockIdx.x;
    const int l = (p & 7) * 96 + (p >> 3);
    const int mi = l / 12;               // 0..63
    const int rzn = l - mi * 12;
    const int wsel = rzn >> 2;
    const int ni = rzn & 3;
    const int m0 = mi * 256;
    const int n0 = ni * 128;
    const unsigned short* Wb = Wt + (size_t)wsel * 262144;

    const int w = t >> 6, lane = t & 63;
    const int wm = (w & 3) * 64, wn = (w >> 2) * 64;
    const int qd = lane >> 4, l16 = lane & 15;

    f32x4 acc[4][4] = {};

    // stage K-tile k0n into buffer slot s (A then B: 6 wave-instrs total)
    auto stage = [&](int k0n, int s) {
        unsigned short* dA = (unsigned short*)(gsmem + s * 49152);
        unsigned short* dB = (unsigned short*)(gsmem + s * 49152 + 32768);
        #pragma unroll
        for (int i = 0; i < 4; ++i) {
            int c = i * 512 + t;
            int row = c >> 3, cc = c & 7;
            int g = cc ^ (row & 7);                   // source-chunk permute
            async_copy16(xb + (size_t)(m0 + row) * 512 + k0n + g * 8, dA + c * 8);
        }
        #pragma unroll
        for (int i = 0; i < 2; ++i) {
            int c = i * 512 + t;
            int row = c >> 3, cc = c & 7;
            int g = cc ^ (row & 7);
            async_copy16(Wb + (size_t)(n0 + row) * 512 + k0n + g * 8, dB + c * 8);
        }
    };

    // prologue: issue P(0), P(1)
    stage(0, 0);
    stage(64, 1);

    int s = 0;
    for (int k0 = 0; k0 < 512; k0 += 64) {
        // P(step) landed: counted wait (last step drains; its loads are 2 steps old)
        if (k0 < 448) { asm volatile("s_waitcnt vmcnt(6)" ::: "memory"); }
        else          { asm volatile("s_waitcnt vmcnt(0)" ::: "memory"); }
        __builtin_amdgcn_s_barrier();
        __builtin_amdgcn_sched_barrier(0);

        // issue P(i+2): its buffer's readers (compute(i-1)) finished pre-barrier
        if (k0 + 128 < 512) {
            int sn = s + 2; if (sn >= 3) sn -= 3;
            stage(k0 + 128, sn);
        }

        // compute buf[s]
        const unsigned short* sA = (const unsigned short*)(gsmem + s * 49152);
        const unsigned short* sB = (const unsigned short*)(gsmem + s * 49152 + 32768);
        #pragma unroll
        for (int ks = 0; ks < 2; ++ks) {
            bf16x8 af[4], bfr[4];
            #pragma unroll
            for (int i = 0; i < 4; ++i) {
                int row = wm + i * 16 + l16;
                int ch = (ks * 4 + qd) ^ (row & 7);       // logical chunk ks*4+qd
                af[i] = *(const bf16x8*)(sA + row * 64 + ch * 8);
            }
            #pragma unroll
            for (int j = 0; j < 4; ++j) {
                int row = wn + j * 16 + l16;
                int ch = (ks * 4 + qd) ^ (row & 7);
                bfr[j] = *(const bf16x8*)(sB + row * 64 + ch * 8);
            }
            #pragma unroll
            for (int i = 0; i < 4; ++i)
                #pragma unroll
                for (int j = 0; j < 4; ++j)
                    acc[i][j] = __builtin_amdgcn_mfma_f32_16x16x32_bf16(af[i], bfr[j], acc[i][j], 0, 0, 0);
        }

        ++s; if (s == 3) s = 0;
    }

    const float* bias = (wsel == 0) ? bq : ((wsel == 1) ? bk : bv);
    __syncthreads();   // all compute done; sT alias of buffer arena safe

    if (wsel < 2) {
        // sT[m][n'] rows 256, stride 136 (16B-aligned: 272 B)
        #pragma unroll
        for (int j = 0; j < 4; ++j) {
            int n = wn + j * 16 + l16;
            float bj = bias[n0 + n];
            #pragma unroll
            for (int i = 0; i < 4; ++i) {
                int mb = wm + i * 16 + qd * 4;
                #pragma unroll
                for (int r = 0; r < 4; ++r)
                    sT[(mb + r) * 136 + n] = f2bf(acc[i][j][r] + bj);
            }
        }
        __syncthreads();
        unsigned short* Og = (wsel == 0) ? Qo : Ko;
        #pragma unroll
        for (int i2 = 0; i2 < 4; ++i2)
            #pragma unroll
            for (int i3 = 0; i3 < 2; ++i3) {
                int m = i2 * 64 + (t >> 3);               // 0..255
                int ch = (t & 7) + i3 * 8;                // 0..15
                bf16x8 v = *(const bf16x8*)(sT + m * 136 + ch * 8);
                *(bf16x8*)(Og + (size_t)(m0 + m) * 512 + n0 + ch * 8) = v;
            }
    } else {
        // sT[n][m'] rows 128, stride 264 (16B-aligned: 528 B)
        #pragma unroll
        for (int j = 0; j < 4; ++j) {
            int n = wn + j * 16 + l16;
            float bj = bias[n0 + n];
            #pragma unroll
            for (int i = 0; i < 4; ++i) {
                int mb = wm + i * 16 + qd * 4;
                #pragma unroll
                for (int r = 0; r < 4; ++r)
                    sT[n * 264 + mb + r] = f2bf(acc[i][j][r] + bj);
            }
        }
        __syncthreads();
        #pragma unroll
        for (int i2 = 0; i2 < 2; ++i2)
            #pragma unroll
            for (int i3 = 0; i3 < 4; ++i3) {
                int n = i2 * 64 + (t >> 3);               // 0..127
                int ch = (t & 7) + i3 * 8;                // 0..31
                bf16x8 v = *(const bf16x8*)(sT + n * 264 + ch * 8);
                *(bf16x8*)(Vt + (size_t)(n0 + n) * M_TOT + m0 + ch * 8) = v;
            }
    }
}

// ---------------------------------------------------------------------------
// Kernel 3: banded attention — v7 (byte-identical to r10's passing version).
__global__ __launch_bounds__(512, 2) void attn(const unsigned short* __restrict__ Qg,
                                               const unsigned short* __restrict__ Kg,
                                               const unsigned short* __restrict__ Vt,
                                               float* __restrict__ out) {
    __shared__ __align__(16) char smem[142592];
    unsigned short* const K0 = (unsigned short*)(smem);
    unsigned short* const K1 = (unsigned short*)(smem + 33280);
    unsigned short* const V0 = (unsigned short*)(smem + 66560);
    unsigned short* const V1 = (unsigned short*)(smem + 99328);
    unsigned short* const sQ = (unsigned short*)(smem + 66560);
    unsigned short* const P0 = (unsigned short*)(smem + 132096);
    unsigned short* const P1 = (unsigned short*)(smem + 137216);
    float* const lsum = (float*)(smem + 142336);

    const int t = threadIdx.x;
    // XCD swizzle over 256 blocks: l = (p&7)*32 + p/8
    const int p = blockIdx.x;
    const int l = (p & 7) * 32 + (p >> 3);
    const int q0 = (l & 63) * 64;        // query offset within batch
    const int b = l >> 6;
    const int bS = b * S_LEN;

    const int w = t >> 6, lane = t & 63;
    const int qd = lane >> 4, l16 = lane & 15;
    const int qh = (w >> 1) * 16;        // q-sub (16 rows)
    const int kh = (w & 1) * 16;         // QK key-half
    const int dh = (w & 1) * 256;        // PV d-half

    if (t < 64) lsum[t] = 0.f;

    // key-tile range
    const int kt_lo = (q0 < 128) ? ((128 - q0) >> 5) : 0;
    int kt_hi = (4192 - q0) >> 5;
    if (kt_hi > 9) kt_hi = 9;

    bf16x8 qreg[16];
    f32x4 oacc[16] = {};   // [dt]

    auto stageK = [&](int key0, unsigned short* dst) {
        #pragma unroll
        for (int i = 0; i < 4; ++i) {
            int c = i * 512 + t;
            int row = c >> 6, cc = c & 63;   // row uniform per wave-instr
            int rowg = key0 + row;
            rowg = (rowg < 0) ? 0 : ((rowg > S_LEN - 1) ? S_LEN - 1 : rowg);
            async_copy16(Kg + (size_t)(bS + rowg) * 512 + cc * 8, dst + row * 520 + cc * 8);
        }
    };
    auto stageV = [&](int key0, unsigned short* dst) {
        #pragma unroll
        for (int i = 0; i < 4; ++i) {
            int c = i * 512 + t;
            int rp = c >> 3, chs = c & 7;
            int ch = chs ^ (rp & 7);         // source pre-swizzle
            int d = rp * 2 + (ch >> 2);
            int kc = ch & 3;
            int kk = key0 + kc * 8;
            int koff = (kk >= 0 && kk + 8 <= S_LEN) ? kk : 0;   // clamped, masked via P=0
            async_copy16(Vt + (size_t)d * M_TOT + bS + koff, dst + c * 8);
        }
    };

    // ---- prologue: K(lo) -> K[lo&1]; Q -> sQ overlay (V area)
    stageK(q0 - HALF_W + kt_lo * 32, (kt_lo & 1) ? K1 : K0);
    #pragma unroll
    for (int i = 0; i < 8; ++i) {
        int c = i * 512 + t;
        int row = c >> 6, cc = c & 63;
        int g = cc ^ (row & 7);
        async_copy16(Qg + (size_t)(bS + q0 + row) * 512 + g * 8, sQ + row * 512 + cc * 8);
    }
    asm volatile("s_waitcnt vmcnt(0)" ::: "memory");   // Q + K(lo) staged
    __builtin_amdgcn_s_barrier();
    // Q fragments to registers (physical chunk = logical ^ (row&7))
    #pragma unroll
    for (int c4 = 0; c4 < 4; ++c4)
        #pragma unroll
        for (int kc = 0; kc < 4; ++kc) {
            int chl = c4 * 16 + kc * 4 + qd;
            int chp = chl ^ (l16 & 7);
            qreg[c4 * 4 + kc] = *(const bf16x8*)(sQ + (qh + l16) * 512 + chp * 8);
        }
    asm volatile("s_waitcnt lgkmcnt(0)" ::: "memory");  // qreg done before V overlays sQ
    __builtin_amdgcn_s_barrier();

    const float scale = 0.04419417382415922f;   // 1/sqrt(512)

    // ---- merged-phase main loop: phase i = QK(i) ∥ PV(i-1)
    for (int i = kt_lo; i <= kt_hi + 1; ++i) {
        const int key0 = q0 - HALF_W + i * 32;

        asm volatile("s_waitcnt vmcnt(0)" ::: "memory");   // K(i), V(i-1) landed
        __builtin_amdgcn_s_barrier();
        __builtin_amdgcn_sched_barrier(0);   // no LDS reads hoist above barrier

        // prefetch: K(i+1) (read next phase), V(i) (read next phase by PV(i))
        if (i + 1 <= kt_hi) stageK(key0 + 32, ((i + 1) & 1) ? K1 : K0);
        if (i <= kt_hi)     stageV(key0,      (i & 1) ? V1 : V0);

        if (i <= kt_hi) {
            // QK(i): S[16q][16k-half] over full D
            const unsigned short* sK = (i & 1) ? K1 : K0;
            f32x4 sacc = {0.f, 0.f, 0.f, 0.f};
            #pragma unroll
            for (int c4 = 0; c4 < 4; ++c4) {
                #pragma unroll
                for (int kc = 0; kc < 4; ++kc) {
                    bf16x8 bk8 = *(const bf16x8*)(sK + (kh + l16) * 520 + c4 * 128 + kc * 32 + qd * 8);
                    sacc = __builtin_amdgcn_mfma_f32_16x16x32_bf16(qreg[c4 * 4 + kc], bk8, sacc, 0, 0, 0);
                }
            }
            // mask + exp + write P[i&1] + row sums
            unsigned short* sPc = (i & 1) ? P1 : P0;
            #pragma unroll
            for (int r = 0; r < 4; ++r) {
                int qi = q0 + qh + qd * 4 + r;
                int kj = key0 + kh + l16;
                bool valid = (kj >= 0) && (kj < S_LEN) && (kj >= qi - HALF_W) && (kj <= qi + HALF_W);
                float p2 = valid ? __expf(sacc[r] * scale) : 0.f;
                sPc[(qh + qd * 4 + r) * 40 + kh + l16] = f2bf(p2);
                float s = p2;
                s += __shfl_xor(s, 1);
                s += __shfl_xor(s, 2);
                s += __shfl_xor(s, 4);
                s += __shfl_xor(s, 8);
                if (l16 == 0) atomicAdd(&lsum[qh + qd * 4 + r], s);
            }
        }

        if (i > kt_lo) {
            // PV(i-1): O[16q][256d-half] += P . V  (independent of QK above)
            const unsigned short* sV  = ((i - 1) & 1) ? V1 : V0;
            const unsigned short* sPp = ((i - 1) & 1) ? P1 : P0;
            bf16x8 ap = *(const bf16x8*)(sPp + (qh + l16) * 40 + qd * 8);
            #pragma unroll
            for (int dt = 0; dt < 16; ++dt) {
                int dv = dh + dt * 16 + l16;
                int rp = dv >> 1;
                int chs = (((dv & 1) << 2) + qd) ^ (rp & 7);
                bf16x8 bv8 = *(const bf16x8*)(sV + rp * 64 + chs * 8);
                oacc[dt] = __builtin_amdgcn_mfma_f32_16x16x32_bf16(ap, bv8, oacc[dt], 0, 0, 0);
            }
        }

        asm volatile("s_waitcnt lgkmcnt(0)" ::: "memory");   // LDS ops drained pre-barrier
    }
    __builtin_amdgcn_s_barrier();   // lsum atomics visible

    // ---- epilogue
    float inv[4];
    #pragma unroll
    for (int r = 0; r < 4; ++r)
        inv[r] = 1.0f / lsum[qh + qd * 4 + r];

    #pragma unroll
    for (int dt = 0; dt < 16; ++dt) {
        int dv = dh + dt * 16 + l16;
        #pragma unroll
        for (int r = 0; r < 4; ++r) {
            int q = qh + qd * 4 + r;
            out[(size_t)(bS + q0 + q) * 512 + dv] = oacc[dt][r] * inv[r];
        }
    }
}

// ---------------------------------------------------------------------------
extern "C" void kernel_launch(void* const* d_in, const int* in_sizes, int n_in,
                              void* d_out, int out_size, void* d_ws, size_t ws_size,
                              hipStream_t stream) {
    const float* x  = (const float*)d_in[0];
    const float* Wq = (const float*)d_in[1];
    const float* bq = (const float*)d_in[2];
    const float* Wk = (const float*)d_in[3];
    const float* bk = (const float*)d_in[4];
    const float* Wv = (const float*)d_in[5];
    const float* bv = (const float*)d_in[6];
    float* out = (float*)d_out;

    char* ws = (char*)d_ws;
    unsigned short* xb = (unsigned short*)(ws);                    // 16 MB
    unsigned short* Wt = (unsigned short*)(ws + 16777216);         // 1.5 MB
    unsigned short* Qb = (unsigned short*)(ws + 18350080);         // 16 MB
    unsigned short* Kb = (unsigned short*)(ws + 35127296);         // 16 MB
    unsigned short* Vt = (unsigned short*)(ws + 51904512);         // 16 MB, [512][16384]

    convert_xw<<<8384, 256, 0, stream>>>(x, Wq, Wk, Wv, xb, Wt);
    qkv_gemm<<<768, 512, 0, stream>>>(xb, Wt, bq, bk, bv, Qb, Kb, Vt);
    attn<<<256, 512, 0, stream>>>(Qb, Kb, Vt, out);
}

// Round 12
// 157.491 us; speedup vs baseline: 1.0211x; 1.0211x over previous
//
#include <hip/hip_runtime.h>
#include <hip/hip_bf16.h>

// Problem constants
#define S_LEN   4096
#define D_MOD   512
#define BATCH   4
#define HALF_W  128
#define M_TOT   (BATCH * S_LEN)   // 16384

typedef __attribute__((ext_vector_type(8))) short bf16x8;
typedef __attribute__((ext_vector_type(4))) float f32x4;

__device__ __forceinline__ unsigned short f2bf(float f) {
    // round-to-nearest-even bf16 (values are finite here)
    unsigned int u = __float_as_uint(f);
    unsigned int r = (u + 0x7fffu + ((u >> 16) & 1u)) >> 16;
    return (unsigned short)r;
}

__device__ __forceinline__ void async_copy16(const void* g, void* l) {
    __builtin_amdgcn_global_load_lds(
        (const __attribute__((address_space(1))) void*)g,
        (__attribute__((address_space(3))) void*)l, 16, 0, 0);
}

// ---------------------------------------------------------------------------
// Kernel 1: fused converts (byte-identical).
__global__ __launch_bounds__(256) void convert_xw(const float* __restrict__ x,
                                                  const float* __restrict__ Wq,
                                                  const float* __restrict__ Wk,
                                                  const float* __restrict__ Wv,
                                                  unsigned short* __restrict__ xb,
                                                  unsigned short* __restrict__ Wt) {
    __shared__ float sT[64][65];
    const int t = threadIdx.x;
    const int bid = blockIdx.x;
    if (bid < 8192) {
        int i = (bid * 256 + t) * 4;
        float4 v = *(const float4*)(x + i);
        ushort4 o;
        o.x = f2bf(v.x); o.y = f2bf(v.y); o.z = f2bf(v.z); o.w = f2bf(v.w);
        *(ushort4*)(xb + i) = o;
        return;
    }
    const int j = bid - 8192;            // 0..191
    const int w = j >> 6;                // weight select (64 tiles each)
    const int rj = j & 63;
    const float* W = (w == 0) ? Wq : ((w == 1) ? Wk : Wv);
    const int n0 = (rj & 7) * 64, k0 = (rj >> 3) * 64;
    const int r = t >> 4, c4 = (t & 15) * 4;
    #pragma unroll
    for (int i = 0; i < 4; ++i) {
        float4 v = *(const float4*)(W + (size_t)(k0 + r + i * 16) * 512 + n0 + c4);
        sT[c4 + 0][r + i * 16] = v.x;
        sT[c4 + 1][r + i * 16] = v.y;
        sT[c4 + 2][r + i * 16] = v.z;
        sT[c4 + 3][r + i * 16] = v.w;
    }
    __syncthreads();
    #pragma unroll
    for (int i = 0; i < 4; ++i) {
        int rr = (t >> 4) + i * 16;   // n-local
        ushort4 o;
        o.x = f2bf(sT[rr][c4 + 0]);
        o.y = f2bf(sT[rr][c4 + 1]);
        o.z = f2bf(sT[rr][c4 + 2]);
        o.w = f2bf(sT[rr][c4 + 3]);
        *(ushort4*)(Wt + (size_t)w * 262144 + (size_t)(n0 + rr) * 512 + k0 + c4) = o;
    }
}

// ---------------------------------------------------------------------------
// Kernel 2: fused QKV GEMM — v4 (byte-identical to r11's passing version):
// depth-2 prefetch, counted vmcnt, 3 LDS buffers.
__global__ __launch_bounds__(512, 1) void qkv_gemm(
    const unsigned short* __restrict__ xb, const unsigned short* __restrict__ Wt,
    const float* __restrict__ bq, const float* __restrict__ bk, const float* __restrict__ bv,
    unsigned short* __restrict__ Qo, unsigned short* __restrict__ Ko,
    unsigned short* __restrict__ Vt) {
    __shared__ __align__(16) char gsmem[147456];
    unsigned short* const sT = (unsigned short*)gsmem;   // epilogue alias

    const int t = threadIdx.x;
    // XCD swizzle over 768 blocks (= 8 * 96)
    const int p = blockIdx.x;
    const int l = (p & 7) * 96 + (p >> 3);
    const int mi = l / 12;               // 0..63
    const int rzn = l - mi * 12;
    const int wsel = rzn >> 2;
    const int ni = rzn & 3;
    const int m0 = mi * 256;
    const int n0 = ni * 128;
    const unsigned short* Wb = Wt + (size_t)wsel * 262144;

    const int w = t >> 6, lane = t & 63;
    const int wm = (w & 3) * 64, wn = (w >> 2) * 64;
    const int qd = lane >> 4, l16 = lane & 15;

    f32x4 acc[4][4] = {};

    // stage K-tile k0n into buffer slot s (A then B: 6 wave-instrs total)
    auto stage = [&](int k0n, int s) {
        unsigned short* dA = (unsigned short*)(gsmem + s * 49152);
        unsigned short* dB = (unsigned short*)(gsmem + s * 49152 + 32768);
        #pragma unroll
        for (int i = 0; i < 4; ++i) {
            int c = i * 512 + t;
            int row = c >> 3, cc = c & 7;
            int g = cc ^ (row & 7);                   // source-chunk permute
            async_copy16(xb + (size_t)(m0 + row) * 512 + k0n + g * 8, dA + c * 8);
        }
        #pragma unroll
        for (int i = 0; i < 2; ++i) {
            int c = i * 512 + t;
            int row = c >> 3, cc = c & 7;
            int g = cc ^ (row & 7);
            async_copy16(Wb + (size_t)(n0 + row) * 512 + k0n + g * 8, dB + c * 8);
        }
    };

    // prologue: issue P(0), P(1)
    stage(0, 0);
    stage(64, 1);

    int s = 0;
    for (int k0 = 0; k0 < 512; k0 += 64) {
        // P(step) landed: counted wait (last step drains; its loads are 2 steps old)
        if (k0 < 448) { asm volatile("s_waitcnt vmcnt(6)" ::: "memory"); }
        else          { asm volatile("s_waitcnt vmcnt(0)" ::: "memory"); }
        __builtin_amdgcn_s_barrier();
        __builtin_amdgcn_sched_barrier(0);

        // issue P(i+2): its buffer's readers (compute(i-1)) finished pre-barrier
        if (k0 + 128 < 512) {
            int sn = s + 2; if (sn >= 3) sn -= 3;
            stage(k0 + 128, sn);
        }

        // compute buf[s]
        const unsigned short* sA = (const unsigned short*)(gsmem + s * 49152);
        const unsigned short* sB = (const unsigned short*)(gsmem + s * 49152 + 32768);
        #pragma unroll
        for (int ks = 0; ks < 2; ++ks) {
            bf16x8 af[4], bfr[4];
            #pragma unroll
            for (int i = 0; i < 4; ++i) {
                int row = wm + i * 16 + l16;
                int ch = (ks * 4 + qd) ^ (row & 7);       // logical chunk ks*4+qd
                af[i] = *(const bf16x8*)(sA + row * 64 + ch * 8);
            }
            #pragma unroll
            for (int j = 0; j < 4; ++j) {
                int row = wn + j * 16 + l16;
                int ch = (ks * 4 + qd) ^ (row & 7);
                bfr[j] = *(const bf16x8*)(sB + row * 64 + ch * 8);
            }
            #pragma unroll
            for (int i = 0; i < 4; ++i)
                #pragma unroll
                for (int j = 0; j < 4; ++j)
                    acc[i][j] = __builtin_amdgcn_mfma_f32_16x16x32_bf16(af[i], bfr[j], acc[i][j], 0, 0, 0);
        }

        ++s; if (s == 3) s = 0;
    }

    const float* bias = (wsel == 0) ? bq : ((wsel == 1) ? bk : bv);
    __syncthreads();   // all compute done; sT alias of buffer arena safe

    if (wsel < 2) {
        // sT[m][n'] rows 256, stride 136 (16B-aligned: 272 B)
        #pragma unroll
        for (int j = 0; j < 4; ++j) {
            int n = wn + j * 16 + l16;
            float bj = bias[n0 + n];
            #pragma unroll
            for (int i = 0; i < 4; ++i) {
                int mb = wm + i * 16 + qd * 4;
                #pragma unroll
                for (int r = 0; r < 4; ++r)
                    sT[(mb + r) * 136 + n] = f2bf(acc[i][j][r] + bj);
            }
        }
        __syncthreads();
        unsigned short* Og = (wsel == 0) ? Qo : Ko;
        #pragma unroll
        for (int i2 = 0; i2 < 4; ++i2)
            #pragma unroll
            for (int i3 = 0; i3 < 2; ++i3) {
                int m = i2 * 64 + (t >> 3);               // 0..255
                int ch = (t & 7) + i3 * 8;                // 0..15
                bf16x8 v = *(const bf16x8*)(sT + m * 136 + ch * 8);
                *(bf16x8*)(Og + (size_t)(m0 + m) * 512 + n0 + ch * 8) = v;
            }
    } else {
        // sT[n][m'] rows 128, stride 264 (16B-aligned: 528 B)
        #pragma unroll
        for (int j = 0; j < 4; ++j) {
            int n = wn + j * 16 + l16;
            float bj = bias[n0 + n];
            #pragma unroll
            for (int i = 0; i < 4; ++i) {
                int mb = wm + i * 16 + qd * 4;
                #pragma unroll
                for (int r = 0; r < 4; ++r)
                    sT[n * 264 + mb + r] = f2bf(acc[i][j][r] + bj);
            }
        }
        __syncthreads();
        #pragma unroll
        for (int i2 = 0; i2 < 2; ++i2)
            #pragma unroll
            for (int i3 = 0; i3 < 4; ++i3) {
                int n = i2 * 64 + (t >> 3);               // 0..127
                int ch = (t & 7) + i3 * 8;                // 0..31
                bf16x8 v = *(const bf16x8*)(sT + n * 264 + ch * 8);
                *(bf16x8*)(Vt + (size_t)(n0 + n) * M_TOT + m0 + ch * 8) = v;
            }
    }
}

// ---------------------------------------------------------------------------
// Kernel 3: banded attention — v8: v7 merged-phase + PHASE-ROTATED tile order.
// Softmax here is order-independent (plain exp, no running max), so each block
// visits its 10 key-tiles in rotated order kt = (i - 2*j) mod 10, j = position
// within the XCD's 32-block chunk. Neighbor blocks (Δq0=64) then read the SAME
// 32-key tile in the SAME phase (64 q-offset = 2 tile-steps), turning the 5-way
// K/V reuse into same-phase L2 hits instead of serial L3 refetches.
// Out-of-window tiles are auto-masked (P=0) — uniform 11-phase loop.
// Pipeline/buffers/numerics identical to v7 (buffers by phase parity).
__global__ __launch_bounds__(512, 2) void attn(const unsigned short* __restrict__ Qg,
                                               const unsigned short* __restrict__ Kg,
                                               const unsigned short* __restrict__ Vt,
                                               float* __restrict__ out) {
    __shared__ __align__(16) char smem[142592];
    unsigned short* const K0 = (unsigned short*)(smem);
    unsigned short* const K1 = (unsigned short*)(smem + 33280);
    unsigned short* const V0 = (unsigned short*)(smem + 66560);
    unsigned short* const V1 = (unsigned short*)(smem + 99328);
    unsigned short* const sQ = (unsigned short*)(smem + 66560);
    unsigned short* const P0 = (unsigned short*)(smem + 132096);
    unsigned short* const P1 = (unsigned short*)(smem + 137216);
    float* const lsum = (float*)(smem + 142336);

    const int t = threadIdx.x;
    // XCD swizzle over 256 blocks: l = (p&7)*32 + p/8
    const int p = blockIdx.x;
    const int l = (p & 7) * 32 + (p >> 3);
    const int q0 = (l & 63) * 64;        // query offset within batch
    const int b = l >> 6;
    const int bS = b * S_LEN;

    const int w = t >> 6, lane = t & 63;
    const int qd = lane >> 4, l16 = lane & 15;
    const int qh = (w >> 1) * 16;        // q-sub (16 rows)
    const int kh = (w & 1) * 16;         // QK key-half
    const int dh = (w & 1) * 256;        // PV d-half

    if (t < 64) lsum[t] = 0.f;

    // rotation: j = position within XCD chunk; kt(phase i) = (i - 2j) mod 10
    const int jl = l & 31;
    const int rot = (2 * jl) % 10;
    int kt = (10 - rot) % 10;            // tile visited at phase 0

    bf16x8 qreg[16];
    f32x4 oacc[16] = {};   // [dt]

    auto stageK = [&](int key0, unsigned short* dst) {
        #pragma unroll
        for (int i = 0; i < 4; ++i) {
            int c = i * 512 + t;
            int row = c >> 6, cc = c & 63;   // row uniform per wave-instr
            int rowg = key0 + row;
            rowg = (rowg < 0) ? 0 : ((rowg > S_LEN - 1) ? S_LEN - 1 : rowg);
            async_copy16(Kg + (size_t)(bS + rowg) * 512 + cc * 8, dst + row * 520 + cc * 8);
        }
    };
    auto stageV = [&](int key0, unsigned short* dst) {
        #pragma unroll
        for (int i = 0; i < 4; ++i) {
            int c = i * 512 + t;
            int rp = c >> 3, chs = c & 7;
            int ch = chs ^ (rp & 7);         // source pre-swizzle
            int d = rp * 2 + (ch >> 2);
            int kc = ch & 3;
            int kk = key0 + kc * 8;
            int koff = (kk >= 0 && kk + 8 <= S_LEN) ? kk : 0;   // clamped, masked via P=0
            async_copy16(Vt + (size_t)d * M_TOT + bS + koff, dst + c * 8);
        }
    };

    // ---- prologue: K(tile kt@phase0) -> K0; Q -> sQ overlay (V area)
    stageK(q0 - HALF_W + kt * 32, K0);
    #pragma unroll
    for (int i = 0; i < 8; ++i) {
        int c = i * 512 + t;
        int row = c >> 6, cc = c & 63;
        int g = cc ^ (row & 7);
        async_copy16(Qg + (size_t)(bS + q0 + row) * 512 + g * 8, sQ + row * 512 + cc * 8);
    }
    asm volatile("s_waitcnt vmcnt(0)" ::: "memory");   // Q + K(phase0) staged
    __builtin_amdgcn_s_barrier();
    // Q fragments to registers (physical chunk = logical ^ (row&7))
    #pragma unroll
    for (int c4 = 0; c4 < 4; ++c4)
        #pragma unroll
        for (int kc = 0; kc < 4; ++kc) {
            int chl = c4 * 16 + kc * 4 + qd;
            int chp = chl ^ (l16 & 7);
            qreg[c4 * 4 + kc] = *(const bf16x8*)(sQ + (qh + l16) * 512 + chp * 8);
        }
    asm volatile("s_waitcnt lgkmcnt(0)" ::: "memory");  // qreg done before V overlays sQ
    __builtin_amdgcn_s_barrier();

    const float scale = 0.04419417382415922f;   // 1/sqrt(512)

    // ---- merged-phase main loop: phase i = QK(kt_i) ∥ PV(kt_{i-1}); 11 phases
    for (int i = 0; i <= 10; ++i) {
        const int key0 = q0 - HALF_W + kt * 32;
        int ktn = kt + 1; if (ktn == 10) ktn = 0;

        asm volatile("s_waitcnt vmcnt(0)" ::: "memory");   // K(i), V(i-1) landed
        __builtin_amdgcn_s_barrier();
        __builtin_amdgcn_sched_barrier(0);   // no LDS reads hoist above barrier

        // prefetch: K(phase i+1), V(phase i)  [v7 buffer-safety pattern]
        if (i + 1 <= 9) stageK(q0 - HALF_W + ktn * 32, ((i + 1) & 1) ? K1 : K0);
        if (i <= 9)     stageV(key0,                    (i & 1) ? V1 : V0);

        if (i <= 9) {
            // QK(kt): S[16q][16k-half] over full D
            const unsigned short* sK = (i & 1) ? K1 : K0;
            f32x4 sacc = {0.f, 0.f, 0.f, 0.f};
            #pragma unroll
            for (int c4 = 0; c4 < 4; ++c4) {
                #pragma unroll
                for (int kc = 0; kc < 4; ++kc) {
                    bf16x8 bk8 = *(const bf16x8*)(sK + (kh + l16) * 520 + c4 * 128 + kc * 32 + qd * 8);
                    sacc = __builtin_amdgcn_mfma_f32_16x16x32_bf16(qreg[c4 * 4 + kc], bk8, sacc, 0, 0, 0);
                }
            }
            // mask + exp + write P[i&1] + row sums (mask kills out-of-window tiles)
            unsigned short* sPc = (i & 1) ? P1 : P0;
            #pragma unroll
            for (int r = 0; r < 4; ++r) {
                int qi = q0 + qh + qd * 4 + r;
                int kj = key0 + kh + l16;
                bool valid = (kj >= 0) && (kj < S_LEN) && (kj >= qi - HALF_W) && (kj <= qi + HALF_W);
                float p2 = valid ? __expf(sacc[r] * scale) : 0.f;
                sPc[(qh + qd * 4 + r) * 40 + kh + l16] = f2bf(p2);
                float s = p2;
                s += __shfl_xor(s, 1);
                s += __shfl_xor(s, 2);
                s += __shfl_xor(s, 4);
                s += __shfl_xor(s, 8);
                if (l16 == 0) atomicAdd(&lsum[qh + qd * 4 + r], s);
            }
        }

        if (i >= 1) {
            // PV(prev phase): O[16q][256d-half] += P . V
            const unsigned short* sV  = ((i - 1) & 1) ? V1 : V0;
            const unsigned short* sPp = ((i - 1) & 1) ? P1 : P0;
            bf16x8 ap = *(const bf16x8*)(sPp + (qh + l16) * 40 + qd * 8);
            #pragma unroll
            for (int dt = 0; dt < 16; ++dt) {
                int dv = dh + dt * 16 + l16;
                int rp = dv >> 1;
                int chs = (((dv & 1) << 2) + qd) ^ (rp & 7);
                bf16x8 bv8 = *(const bf16x8*)(sV + rp * 64 + chs * 8);
                oacc[dt] = __builtin_amdgcn_mfma_f32_16x16x32_bf16(ap, bv8, oacc[dt], 0, 0, 0);
            }
        }

        asm volatile("s_waitcnt lgkmcnt(0)" ::: "memory");   // LDS ops drained pre-barrier
        kt = ktn;
    }
    __builtin_amdgcn_s_barrier();   // lsum atomics visible

    // ---- epilogue
    float inv[4];
    #pragma unroll
    for (int r = 0; r < 4; ++r)
        inv[r] = 1.0f / lsum[qh + qd * 4 + r];

    #pragma unroll
    for (int dt = 0; dt < 16; ++dt) {
        int dv = dh + dt * 16 + l16;
        #pragma unroll
        for (int r = 0; r < 4; ++r) {
            int q = qh + qd * 4 + r;
            out[(size_t)(bS + q0 + q) * 512 + dv] = oacc[dt][r] * inv[r];
        }
    }
}

// ---------------------------------------------------------------------------
extern "C" void kernel_launch(void* const* d_in, const int* in_sizes, int n_in,
                              void* d_out, int out_size, void* d_ws, size_t ws_size,
                              hipStream_t stream) {
    const float* x  = (const float*)d_in[0];
    const float* Wq = (const float*)d_in[1];
    const float* bq = (const float*)d_in[2];
    const float* Wk = (const float*)d_in[3];
    const float* bk = (const float*)d_in[4];
    const float* Wv = (const float*)d_in[5];
    const float* bv = (const float*)d_in[6];
    float* out = (float*)d_out;

    char* ws = (char*)d_ws;
    unsigned short* xb = (unsigned short*)(ws);                    // 16 MB
    unsigned short* Wt = (unsigned short*)(ws + 16777216);         // 1.5 MB
    unsigned short* Qb = (unsigned short*)(ws + 18350080);         // 16 MB
    unsigned short* Kb = (unsigned short*)(ws + 35127296);         // 16 MB
    unsigned short* Vt = (unsigned short*)(ws + 51904512);         // 16 MB, [512][16384]

    convert_xw<<<8384, 256, 0, stream>>>(x, Wq, Wk, Wv, xb, Wt);
    qkv_gemm<<<768, 512, 0, stream>>>(xb, Wt, bq, bk, bv, Qb, Kb, Vt);
    attn<<<256, 512, 0, stream>>>(Qb, Kb, Vt, out);
}